// Round 1
// baseline (2266.323 us; speedup 1.0000x reference)
//
#include <hip/hip_runtime.h>
#include <stdint.h>

#define T_LEN 2048
#define N_TAG 128

typedef __attribute__((ext_vector_type(4))) float f32x4;
typedef __attribute__((ext_vector_type(8))) short bf16x8;
typedef __attribute__((ext_vector_type(4))) uint32_t u32x4;

template <int S>
struct IC {
  static constexpr int value = S;
};

// pack two fp32 -> one dword of two bf16 (round-half-up), elem0 in low half
__device__ __forceinline__ uint32_t pack2_bf16(float a, float b) {
  uint32_t ua = __float_as_uint(a) + 0x8000u;
  uint32_t ub = __float_as_uint(b) + 0x8000u;
  // v_perm_b32: src0 = HI dword (bytes 7:4), src1 = LO dword (bytes 3:0)
  // dst = [ub.b3 ub.b2 ua.b3 ua.b2] -> lo16 = bf16(a), hi16 = bf16(b)
  return __builtin_amdgcn_perm(ua, ub, 0x03020706u);
}

// 16 batches per wave, 1 wave per block, 4 blocks.
// State S (linear domain, per-batch pow2 offset L) lives in LDS a_lds[b][i].
// Per step: A = (S * e^em) as bf16, D[b][j] = A @ E via 32x mfma 16x16x32_bf16.
// E = exp(transitions) preloaded in B-fragment layout in VGPRs.
__global__ __launch_bounds__(64, 1) void crf_fwd_kernel(
    const float* __restrict__ em, const int* __restrict__ lens,
    const float* __restrict__ trans, const float* __restrict__ head,
    const float* __restrict__ last, float* __restrict__ out) {
  const int lane = threadIdx.x & 63;
  const int c = lane & 15;  // A-side batch index / D-side col-in-tile
  const int q = lane >> 4;  // quad
  const int b0 = (int)blockIdx.x * 16;

  __shared__ float a_lds[16][132];  // [batch][i], padded stride
  __shared__ int k_lds[16];         // per-batch rescale exponent

  // ---- preload E fragments (B operand): lane holds k = kt*32+q*8+jj, n = jt*16+c
  bf16x8 efrag[8][4];
#pragma unroll
  for (int jt = 0; jt < 8; ++jt) {
#pragma unroll
    for (int kt = 0; kt < 4; ++kt) {
      u32x4 w;
#pragma unroll
      for (int p = 0; p < 4; ++p) {
        const int i0 = kt * 32 + q * 8 + 2 * p;
        const float v0 = __expf(trans[(i0 + 0) * N_TAG + jt * 16 + c]);
        const float v1 = __expf(trans[(i0 + 1) * N_TAG + jt * 16 + c]);
        w[p] = pack2_bf16(v0, v1);
      }
      efrag[jt][kt] = __builtin_bit_cast(bf16x8, w);
    }
  }

  float lastx[8];
#pragma unroll
  for (int jt = 0; jt < 8; ++jt) lastx[jt] = __expf(last[jt * 16 + c]);

  int lenr[4];
  float L[4];
#pragma unroll
  for (int r = 0; r < 4; ++r) {
    lenr[r] = lens[b0 + 4 * q + r];
    L[r] = 0.f;
  }

  // D_0[b][j] = e^{head[j]}  (em_0 is applied A-side at step 1)
  f32x4 acc[8];
#pragma unroll
  for (int jt = 0; jt < 8; ++jt) {
    const float hv = __expf(head[jt * 16 + c]);
    acc[jt] = (f32x4){hv, hv, hv, hv};
  }

  // em prefetch buffers: slot holds raw em row (t-1) for step t == slot (mod 4)
  float4 embuf[4][8];

  auto issue_em = [&](int row, int slot) {
    const float4* p =
        (const float4*)(em + ((size_t)(b0 + c) * T_LEN + row) * N_TAG + q * 8);
#pragma unroll
    for (int kt = 0; kt < 4; ++kt) {
      embuf[slot][kt * 2 + 0] = p[kt * 8 + 0];
      embuf[slot][kt * 2 + 1] = p[kt * 8 + 1];
    }
  };

  // capture: out_b = log(sum_j acc[b][j] * e^{em[b][t][j]} * e^{last[j]}) + L_b
  auto capture_check = [&](int t) {
#pragma unroll
    for (int r = 0; r < 4; ++r) {
      if (t == lenr[r] - 1) {
        const int b = b0 + 4 * q + r;
        float s = 0.f;
#pragma unroll
        for (int jt = 0; jt < 8; ++jt) {
          const float ee =
              __expf(em[((size_t)b * T_LEN + t) * N_TAG + jt * 16 + c]);
          s += acc[jt][r] * lastx[jt] * ee;
        }
        s += __shfl_xor(s, 1);
        s += __shfl_xor(s, 2);
        s += __shfl_xor(s, 4);
        s += __shfl_xor(s, 8);
        if (c == 0) out[b] = __logf(s) + L[r];
      }
    }
  };

  capture_check(0);

#pragma unroll
  for (int jt = 0; jt < 8; ++jt)
#pragma unroll
    for (int r = 0; r < 4; ++r) a_lds[4 * q + r][jt * 16 + c] = acc[jt][r];
  if (lane < 16) k_lds[lane] = 0;

  issue_em(0, 1);
  issue_em(1, 2);
  issue_em(2, 3);

  const f32x4 vzero = (f32x4){0.f, 0.f, 0.f, 0.f};

  auto step = [&](auto slotc, int t) {
    constexpr int SLOT = decltype(slotc)::value;
    // prefetch em row (t+2) (used at step t+3) into slot (t+3)&3
    {
      int row = t + 2;
      if (row > T_LEN - 1) row = T_LEN - 1;
      issue_em(row, (SLOT + 3) & 3);
    }
    int esc = 0;
    if (SLOT == 1) esc = k_lds[c];  // rescale exponent from step t-1 (SLOT 0)
#pragma unroll
    for (int kt = 0; kt < 4; ++kt) {
      float4 s0 = *(const float4*)&a_lds[c][kt * 32 + q * 8];
      float4 s1 = *(const float4*)&a_lds[c][kt * 32 + q * 8 + 4];
      if (SLOT == 1) {
        s0.x = ldexpf(s0.x, -esc);
        s0.y = ldexpf(s0.y, -esc);
        s0.z = ldexpf(s0.z, -esc);
        s0.w = ldexpf(s0.w, -esc);
        s1.x = ldexpf(s1.x, -esc);
        s1.y = ldexpf(s1.y, -esc);
        s1.z = ldexpf(s1.z, -esc);
        s1.w = ldexpf(s1.w, -esc);
      }
      const float4 m0 = embuf[SLOT][kt * 2 + 0];
      const float4 m1 = embuf[SLOT][kt * 2 + 1];
      const float p0 = s0.x * __expf(m0.x);
      const float p1 = s0.y * __expf(m0.y);
      const float p2 = s0.z * __expf(m0.z);
      const float p3 = s0.w * __expf(m0.w);
      const float p4 = s1.x * __expf(m1.x);
      const float p5 = s1.y * __expf(m1.y);
      const float p6 = s1.z * __expf(m1.z);
      const float p7 = s1.w * __expf(m1.w);
      u32x4 w;
      w[0] = pack2_bf16(p0, p1);
      w[1] = pack2_bf16(p2, p3);
      w[2] = pack2_bf16(p4, p5);
      w[3] = pack2_bf16(p6, p7);
      const bf16x8 af = __builtin_bit_cast(bf16x8, w);
#pragma unroll
      for (int jt = 0; jt < 8; ++jt) {
        acc[jt] = __builtin_amdgcn_mfma_f32_16x16x32_bf16(
            af, efrag[jt][kt], (kt == 0) ? vzero : acc[jt], 0, 0, 0);
      }
    }
    capture_check(t);
    if (SLOT == 0) {  // rescale bookkeeping every 4th step
#pragma unroll
      for (int r = 0; r < 4; ++r) {
        float m =
            fmaxf(fmaxf(fmaxf(acc[0][r], acc[1][r]), fmaxf(acc[2][r], acc[3][r])),
                  fmaxf(fmaxf(acc[4][r], acc[5][r]), fmaxf(acc[6][r], acc[7][r])));
        m = fmaxf(m, __shfl_xor(m, 1));
        m = fmaxf(m, __shfl_xor(m, 2));
        m = fmaxf(m, __shfl_xor(m, 4));
        m = fmaxf(m, __shfl_xor(m, 8));
        const int e = (int)(__float_as_uint(m) >> 23) - 126;
        L[r] += (float)e * 0.6931471805599453f;
        if (c == r) k_lds[4 * q + r] = e;
      }
    }
    // write new state
#pragma unroll
    for (int jt = 0; jt < 8; ++jt)
#pragma unroll
      for (int r = 0; r < 4; ++r) a_lds[4 * q + r][jt * 16 + c] = acc[jt][r];
  };

  int t = 1;
#pragma unroll 1
  for (int it = 0; it < 511; ++it) {  // t = 1 .. 2044
    step(IC<1>{}, t);
    step(IC<2>{}, t + 1);
    step(IC<3>{}, t + 2);
    step(IC<0>{}, t + 3);
    t += 4;
  }
  step(IC<1>{}, t);      // 2045
  step(IC<2>{}, t + 1);  // 2046
  step(IC<3>{}, t + 2);  // 2047
}

extern "C" void kernel_launch(void* const* d_in, const int* in_sizes, int n_in,
                              void* d_out, int out_size, void* d_ws,
                              size_t ws_size, hipStream_t stream) {
  const float* em = (const float*)d_in[0];
  const int* lens = (const int*)d_in[1];
  const float* trans = (const float*)d_in[2];
  const float* head = (const float*)d_in[3];
  const float* last = (const float*)d_in[4];
  float* out = (float*)d_out;
  crf_fwd_kernel<<<4, 64, 0, stream>>>(em, lens, trans, head, last, out);
}

// Round 2
// 1443.667 us; speedup vs baseline: 1.5698x; 1.5698x over previous
//
#include <hip/hip_runtime.h>
#include <stdint.h>

#define T_LEN 2048
#define B_TOT 64
#define N_TAG 128
#define LSTRIDE 136  // bf16 units per LDS row (128 + 8 pad, keeps 16B align)

typedef __attribute__((ext_vector_type(4))) float f32x4;
typedef __attribute__((ext_vector_type(8))) short bf16x8;
typedef __attribute__((ext_vector_type(4))) uint32_t u32x4;
typedef __attribute__((ext_vector_type(2))) uint32_t u32x2;

template <int S>
struct IC {
  static constexpr int value = S;
};

// pack two fp32 -> dword of two bf16 (round-half-up); elem0 in low half
__device__ __forceinline__ uint32_t pack2_bf16(float a, float b) {
  uint32_t ua = __float_as_uint(a) + 0x8000u;
  uint32_t ub = __float_as_uint(b) + 0x8000u;
  return __builtin_amdgcn_perm(ua, ub, 0x03020706u);
}
__device__ __forceinline__ float bf_lo(uint32_t w) {
  return __uint_as_float(w << 16);
}
__device__ __forceinline__ float bf_hi(uint32_t w) {
  return __uint_as_float(w & 0xffff0000u);
}

// prepass: ws[t][b][i] = bf16(exp(em[b][t][i])); write-linear, read 512B rows
__global__ void eem_prepass(const float* __restrict__ em,
                            uint32_t* __restrict__ ws) {
  const int tid = blockIdx.x * blockDim.x + threadIdx.x;  // 0 .. 2^23-1
  const int t = tid >> 12;          // 4096 bf16-pairs per timestep
  const int rem = tid & 4095;
  const int b = rem >> 6;
  const int i = (rem & 63) << 1;
  const float2 v = *(const float2*)(em + ((size_t)b * T_LEN + t) * N_TAG + i);
  ws[tid] = pack2_bf16(__expf(v.x), __expf(v.y));
}

// 16 batches/wave, 1 wave/block, 4 blocks. State stored in LDS as
// bf16(acc * eem) -- mfma-ready B fragments, zero VALU on the read path.
// A = E^T (constant, in regs). D[j][b] -> vector LDS stores.
__global__ __launch_bounds__(64, 1) void crf_fwd_kernel(
    const float* __restrict__ em, const int* __restrict__ lens,
    const float* __restrict__ trans, const float* __restrict__ head,
    const float* __restrict__ last, const uint16_t* __restrict__ eem,
    float* __restrict__ out) {
  const int lane = threadIdx.x & 63;
  const int c = lane & 15;  // batch-in-tile (B side n, D col); A side m=j tile idx
  const int q = lane >> 4;
  const int b0 = (int)blockIdx.x * 16;
  const int bg = b0 + c;

  __shared__ __align__(16) uint16_t s_lds[16][LSTRIDE];

  // A fragments: A[m=j=jt*16+c][k=i=kt*32+q*8+jj] = exp(trans[i*N + j])
  bf16x8 efrag[8][4];
#pragma unroll
  for (int jt = 0; jt < 8; ++jt) {
#pragma unroll
    for (int kt = 0; kt < 4; ++kt) {
      u32x4 w;
#pragma unroll
      for (int p = 0; p < 4; ++p) {
        const int i0 = kt * 32 + q * 8 + 2 * p;
        const float v0 = __expf(trans[(i0 + 0) * N_TAG + jt * 16 + c]);
        const float v1 = __expf(trans[(i0 + 1) * N_TAG + jt * 16 + c]);
        w[p] = pack2_bf16(v0, v1);
      }
      efrag[jt][kt] = __builtin_bit_cast(bf16x8, w);
    }
  }

  const int len = lens[bg];
  float L = 0.f;

  // initial state: S0[b][i] = bf16(e^{head_i} * e^{em[b][0][i]})
#pragma unroll
  for (int kt = 0; kt < 4; ++kt) {
    u32x4 w;
#pragma unroll
    for (int p = 0; p < 4; ++p) {
      const int i0 = kt * 32 + q * 8 + 2 * p;
      const float h0 = __expf(head[i0]) *
                       __expf(em[(size_t)bg * T_LEN * N_TAG + i0]);
      const float h1 = __expf(head[i0 + 1]) *
                       __expf(em[(size_t)bg * T_LEN * N_TAG + i0 + 1]);
      w[p] = pack2_bf16(h0, h1);
    }
    *(u32x4*)(&s_lds[c][kt * 32 + q * 8]) = w;
  }

  // len==1 edge (setup guarantees len>=1024, but keep it correct)
  if (len == 1) {
    float s = 0.f;
#pragma unroll
    for (int kt = 0; kt < 4; ++kt)
#pragma unroll
      for (int jj = 0; jj < 8; ++jj) {
        const int i = kt * 32 + q * 8 + jj;
        s += __expf(head[i] + em[(size_t)bg * T_LEN * N_TAG + i] + last[i]);
      }
    s += __shfl_xor(s, 16);
    s += __shfl_xor(s, 32);
    if (q == 0) out[bg] = __logf(s);
  }

  // eem prefetch: slot t&3 holds row t (D-layout pattern: j = jt*16+q*4+r)
  u32x2 embuf[4][8];
  auto issue_eem = [&](int row, int slot) {
    const uint16_t* p =
        eem + (size_t)row * (B_TOT * N_TAG) + (size_t)bg * N_TAG + q * 4;
#pragma unroll
    for (int jt = 0; jt < 8; ++jt)
      embuf[slot][jt] = *(const u32x2*)(p + jt * 16);
  };
  issue_eem(1, 1);
  issue_eem(2, 2);
  issue_eem(3, 3);

  f32x4 acc[8];
  const f32x4 vzero = (f32x4){0.f, 0.f, 0.f, 0.f};

  auto step = [&](auto slotc, int t) {
    constexpr int SLOT = decltype(slotc)::value;
    // prefetch row t+3 into slot (t-1)&3 (freed last step)
    {
      int row = t + 3;
      if (row > T_LEN - 1) row = T_LEN - 1;
      issue_eem(row, (SLOT + 3) & 3);
    }
    // B fragments straight from LDS -- no VALU
    bf16x8 bf[4];
#pragma unroll
    for (int kt = 0; kt < 4; ++kt)
      bf[kt] = *(const bf16x8*)(&s_lds[c][kt * 32 + q * 8]);
#pragma unroll
    for (int kt = 0; kt < 4; ++kt)
#pragma unroll
      for (int jt = 0; jt < 8; ++jt)
        acc[jt] = __builtin_amdgcn_mfma_f32_16x16x32_bf16(
            efrag[jt][kt], bf[kt], (kt == 0) ? vzero : acc[jt], 0, 0, 0);
    // capture: out_b = log(sum_j acc[j] * eem_t[j] * e^{last_j}) + L
    if (t == len - 1) {
      float s = 0.f;
#pragma unroll
      for (int jt = 0; jt < 8; ++jt) {
        const u32x2 ed = embuf[SLOT][jt];
        const int j = jt * 16 + q * 4;
        s += acc[jt][0] * bf_lo(ed[0]) * __expf(last[j + 0]);
        s += acc[jt][1] * bf_hi(ed[0]) * __expf(last[j + 1]);
        s += acc[jt][2] * bf_lo(ed[1]) * __expf(last[j + 2]);
        s += acc[jt][3] * bf_hi(ed[1]) * __expf(last[j + 3]);
      }
      s += __shfl_xor(s, 16);
      s += __shfl_xor(s, 32);
      if (q == 0) out[bg] = __logf(s) + L;
    }
    int e = 0;
    if (SLOT == 0) {  // rescale bookkeeping every 4th step
      float m = acc[0][0];
#pragma unroll
      for (int jt = 0; jt < 8; ++jt) {
        const float m4 = fmaxf(fmaxf(acc[jt][0], acc[jt][1]),
                               fmaxf(acc[jt][2], acc[jt][3]));
        m = (jt == 0) ? m4 : fmaxf(m, m4);
      }
      m = fmaxf(m, __shfl_xor(m, 16));
      m = fmaxf(m, __shfl_xor(m, 32));
      e = (int)(__float_as_uint(m) >> 23) - 126;
      L += (float)e * 0.6931471805599453f;
    }
    // store phase: state' = bf16(acc * eem_t [* 2^-e]) in B-fragment order
#pragma unroll
    for (int jt = 0; jt < 8; ++jt) {
      const u32x2 ed = embuf[SLOT][jt];
      float p0 = acc[jt][0] * bf_lo(ed[0]);
      float p1 = acc[jt][1] * bf_hi(ed[0]);
      float p2 = acc[jt][2] * bf_lo(ed[1]);
      float p3 = acc[jt][3] * bf_hi(ed[1]);
      if (SLOT == 0) {
        p0 = ldexpf(p0, -e);
        p1 = ldexpf(p1, -e);
        p2 = ldexpf(p2, -e);
        p3 = ldexpf(p3, -e);
      }
      u32x2 w;
      w[0] = pack2_bf16(p0, p1);
      w[1] = pack2_bf16(p2, p3);
      *(u32x2*)(&s_lds[c][jt * 16 + q * 4]) = w;
    }
  };

  int t = 1;
#pragma unroll 1
  for (int it = 0; it < 511; ++it) {  // t = 1 .. 2044
    step(IC<1>{}, t);
    step(IC<2>{}, t + 1);
    step(IC<3>{}, t + 2);
    step(IC<0>{}, t + 3);
    t += 4;
  }
  step(IC<1>{}, t);      // 2045
  step(IC<2>{}, t + 1);  // 2046
  step(IC<3>{}, t + 2);  // 2047
}

extern "C" void kernel_launch(void* const* d_in, const int* in_sizes, int n_in,
                              void* d_out, int out_size, void* d_ws,
                              size_t ws_size, hipStream_t stream) {
  const float* em = (const float*)d_in[0];
  const int* lens = (const int*)d_in[1];
  const float* trans = (const float*)d_in[2];
  const float* head = (const float*)d_in[3];
  const float* last = (const float*)d_in[4];
  float* out = (float*)d_out;
  uint32_t* ws = (uint32_t*)d_ws;  // 2048*64*128 bf16 = 32 MiB

  eem_prepass<<<32768, 256, 0, stream>>>(em, ws);
  crf_fwd_kernel<<<4, 64, 0, stream>>>(em, lens, trans, head, last,
                                       (const uint16_t*)ws, out);
}

// Round 3
// 935.745 us; speedup vs baseline: 2.4219x; 1.5428x over previous
//
#include <hip/hip_runtime.h>
#include <stdint.h>

#define T_LEN 2048
#define B_TOT 64
#define N_TAG 128
#define LSTRIDE 136  // bf16 units per LDS row (128 + 8 pad, keeps 16B align)

typedef __attribute__((ext_vector_type(4))) float f32x4;
typedef __attribute__((ext_vector_type(8))) short bf16x8;
typedef __attribute__((ext_vector_type(4))) uint32_t u32x4;
typedef __attribute__((ext_vector_type(2))) uint32_t u32x2;

template <int S>
struct IC {
  static constexpr int value = S;
};

// pack two fp32 -> dword of two bf16 (round-half-up); elem0 in low half
__device__ __forceinline__ uint32_t pack2_bf16(float a, float b) {
  uint32_t ua = __float_as_uint(a) + 0x8000u;
  uint32_t ub = __float_as_uint(b) + 0x8000u;
  return __builtin_amdgcn_perm(ua, ub, 0x03020706u);
}
__device__ __forceinline__ float bf_lo(uint32_t w) {
  return __uint_as_float(w << 16);
}
__device__ __forceinline__ float bf_hi(uint32_t w) {
  return __uint_as_float(w & 0xffff0000u);
}

// prepass: ws[t][b][i] = bf16(exp(em[b][t][i]))
__global__ void eem_prepass(const float* __restrict__ em,
                            uint32_t* __restrict__ ws) {
  const int tid = blockIdx.x * blockDim.x + threadIdx.x;  // 0 .. 2^23-1
  const int t = tid >> 12;  // 4096 bf16-pairs per timestep
  const int rem = tid & 4095;
  const int b = rem >> 6;
  const int i = (rem & 63) << 1;
  const float2 v = *(const float2*)(em + ((size_t)b * T_LEN + t) * N_TAG + i);
  ws[tid] = pack2_bf16(__expf(v.x), __expf(v.y));
}

// 16 batches/block, 2 waves/block (jt-split), 4 blocks.
// State = bf16(acc * eem), ping-pong LDS buffers, MFMA B-fragment layout.
// A = E (constant, regs/AGPRs). Rescale: exponent probe of j=0, deferred 1 step.
__global__ __launch_bounds__(128, 1) void crf_fwd_kernel(
    const float* __restrict__ em, const int* __restrict__ lens,
    const float* __restrict__ trans, const float* __restrict__ head,
    const float* __restrict__ last, const uint16_t* __restrict__ eem,
    float* __restrict__ out) {
  const int lane = threadIdx.x & 63;
  const int w = threadIdx.x >> 6;  // wave id: owns jt = w*4 .. w*4+3
  const int c = lane & 15;         // batch-in-tile
  const int q = lane >> 4;
  const int b0 = (int)blockIdx.x * 16;
  const int bg = b0 + c;
  const int jb = w * 4;

  __shared__ __align__(16) uint16_t s_lds[2][16][LSTRIDE];
  __shared__ int k_lds[16];
  __shared__ float cap_lds[2][16];

  // A fragments for this wave: A[m=c][k=kt*32+q*8+jj] = exp(trans[k*N + (jb+jtl)*16 + c])
  bf16x8 efrag[4][4];
#pragma unroll
  for (int jtl = 0; jtl < 4; ++jtl) {
    const int j = (jb + jtl) * 16 + c;
#pragma unroll
    for (int kt = 0; kt < 4; ++kt) {
      u32x4 wd;
#pragma unroll
      for (int p = 0; p < 4; ++p) {
        const int i0 = kt * 32 + q * 8 + 2 * p;
        const float v0 = __expf(trans[(i0 + 0) * N_TAG + j]);
        const float v1 = __expf(trans[(i0 + 1) * N_TAG + j]);
        wd[p] = pack2_bf16(v0, v1);
      }
      efrag[jtl][kt] = __builtin_bit_cast(bf16x8, wd);
    }
  }

  const int len = lens[bg];
  float L = 0.f;
  float Lcap = 0.f;

  // initial state S0[b][i] = bf16(e^{head_i} * e^{em[b][0][i]}), wave w covers
  // i in [w*64, w*64+64), into buffer 0
#pragma unroll
  for (int kt2 = 0; kt2 < 2; ++kt2) {
    const int kt = w * 2 + kt2;
    u32x4 wd;
#pragma unroll
    for (int p = 0; p < 4; ++p) {
      const int i0 = kt * 32 + q * 8 + 2 * p;
      const float h0 =
          __expf(head[i0]) * __expf(em[(size_t)bg * T_LEN * N_TAG + i0]);
      const float h1 =
          __expf(head[i0 + 1]) * __expf(em[(size_t)bg * T_LEN * N_TAG + i0 + 1]);
      wd[p] = pack2_bf16(h0, h1);
    }
    *(u32x4*)(&s_lds[0][c][kt * 32 + q * 8]) = wd;
  }
  if (threadIdx.x < 16) k_lds[threadIdx.x] = 0;

  // eem prefetch: slot t&3 holds row t, this wave's jt range
  u32x2 embuf[4][4];
  auto issue_eem = [&](int row, int slot) {
    const uint16_t* p =
        eem + (size_t)row * (B_TOT * N_TAG) + (size_t)bg * N_TAG + q * 4;
#pragma unroll
    for (int jtl = 0; jtl < 4; ++jtl)
      embuf[slot][jtl] = *(const u32x2*)(p + (jb + jtl) * 16);
  };
  issue_eem(1, 1);
  issue_eem(2, 2);
  issue_eem(3, 3);

  __syncthreads();

  f32x4 acc[4];
  const f32x4 vzero = (f32x4){0.f, 0.f, 0.f, 0.f};

  auto step = [&](auto slotc, int t) {
    constexpr int SLOT = decltype(slotc)::value;
    constexpr int RP = (SLOT + 1) & 1;  // read buffer (state of step t-1)
    constexpr int WP = SLOT & 1;        // write buffer
    int e = 0;
    if (SLOT == 1) e = k_lds[c];  // rescale exponent from last SLOT0 step
    // B fragments straight from LDS -- no VALU on read path
    bf16x8 bf[4];
#pragma unroll
    for (int kt = 0; kt < 4; ++kt)
      bf[kt] = *(const bf16x8*)(&s_lds[RP][c][kt * 32 + q * 8]);
    // prefetch eem row t+3 into the slot freed last step
    {
      int row = t + 3;
      if (row > T_LEN - 1) row = T_LEN - 1;
      issue_eem(row, (SLOT + 3) & 3);
    }
#pragma unroll
    for (int kt = 0; kt < 4; ++kt)
#pragma unroll
      for (int jtl = 0; jtl < 4; ++jtl)
        acc[jtl] = __builtin_amdgcn_mfma_f32_16x16x32_bf16(
            efrag[jtl][kt], bf[kt], (kt == 0) ? vzero : acc[jtl], 0, 0, 0);
    // capture partial: sum over this wave's j of acc * eem_t * e^{last}
    if (t == len - 1) {
      float s = 0.f;
#pragma unroll
      for (int jtl = 0; jtl < 4; ++jtl) {
        const u32x2 ed = embuf[SLOT][jtl];
        const int j0 = (jb + jtl) * 16 + q * 4;
        s += acc[jtl][0] * bf_lo(ed[0]) * __expf(last[j0 + 0]);
        s += acc[jtl][1] * bf_hi(ed[0]) * __expf(last[j0 + 1]);
        s += acc[jtl][2] * bf_lo(ed[1]) * __expf(last[j0 + 2]);
        s += acc[jtl][3] * bf_hi(ed[1]) * __expf(last[j0 + 3]);
      }
      s += __shfl_xor(s, 16);
      s += __shfl_xor(s, 32);
      if (q == 0) cap_lds[w][c] = s;
      Lcap = L;  // acc carries scale L (pre-update)
    }
    if (SLOT == 0) {
      // exponent probe of j=0 (all alpha_j within ~2^15 of each other)
      if (threadIdx.x < 16)
        k_lds[c] = (int)(__float_as_uint(acc[0][0]) >> 23) - 126;
    }
    if (SLOT == 1) L += (float)e * 0.6931471805599453f;
    // store: state' = bf16(acc * eem_t [* 2^-e]) in B-fragment order
#pragma unroll
    for (int jtl = 0; jtl < 4; ++jtl) {
      const u32x2 ed = embuf[SLOT][jtl];
      float p0 = acc[jtl][0] * bf_lo(ed[0]);
      float p1 = acc[jtl][1] * bf_hi(ed[0]);
      float p2 = acc[jtl][2] * bf_lo(ed[1]);
      float p3 = acc[jtl][3] * bf_hi(ed[1]);
      if (SLOT == 1) {
        p0 = ldexpf(p0, -e);
        p1 = ldexpf(p1, -e);
        p2 = ldexpf(p2, -e);
        p3 = ldexpf(p3, -e);
      }
      u32x2 wd;
      wd[0] = pack2_bf16(p0, p1);
      wd[1] = pack2_bf16(p2, p3);
      *(u32x2*)(&s_lds[WP][c][(jb + jtl) * 16 + q * 4]) = wd;
    }
    __syncthreads();
    // combine capture partials (both waves' halves) after the barrier
    if (t == len - 1 && threadIdx.x < 16) {
      out[bg] = __logf(cap_lds[0][c] + cap_lds[1][c]) + Lcap;
    }
  };

  int t = 1;
#pragma unroll 1
  for (int it = 0; it < 511; ++it) {  // t = 1 .. 2044
    step(IC<1>{}, t);
    step(IC<2>{}, t + 1);
    step(IC<3>{}, t + 2);
    step(IC<0>{}, t + 3);
    t += 4;
  }
  step(IC<1>{}, t);      // 2045
  step(IC<2>{}, t + 1);  // 2046
  step(IC<3>{}, t + 2);  // 2047
}

extern "C" void kernel_launch(void* const* d_in, const int* in_sizes, int n_in,
                              void* d_out, int out_size, void* d_ws,
                              size_t ws_size, hipStream_t stream) {
  const float* em = (const float*)d_in[0];
  const int* lens = (const int*)d_in[1];
  const float* trans = (const float*)d_in[2];
  const float* head = (const float*)d_in[3];
  const float* last = (const float*)d_in[4];
  float* out = (float*)d_out;
  uint32_t* ws = (uint32_t*)d_ws;  // 2048*64*128 bf16 = 32 MiB

  eem_prepass<<<32768, 256, 0, stream>>>(em, ws);
  crf_fwd_kernel<<<4, 128, 0, stream>>>(em, lens, trans, head, last,
                                        (const uint16_t*)ws, out);
}

// Round 4
// 685.114 us; speedup vs baseline: 3.3080x; 1.3658x over previous
//
#include <hip/hip_runtime.h>
#include <stdint.h>

#define T_LEN 2048
#define N_TAG 128

typedef __attribute__((ext_vector_type(4))) float f32x4;
typedef __attribute__((ext_vector_type(8))) short bf16x8;
typedef __attribute__((ext_vector_type(4))) uint32_t u32x4;

template <int S>
struct IC {
  static constexpr int value = S;
};

// pack two fp32 -> dword of two bf16 (round-half-up); elem0 in low half
__device__ __forceinline__ uint32_t pack2_bf16(float a, float b) {
  uint32_t ua = __float_as_uint(a) + 0x8000u;
  uint32_t ub = __float_as_uint(b) + 0x8000u;
  return __builtin_amdgcn_perm(ua, ub, 0x03020706u);
}

// 16 batches/block, 4 waves/block (j-split: wave w owns j in [32w,32w+32)),
// 4 blocks. A-operand rows are PERMUTED (j = 32w + (m>>2)*8 + tl*4 + (m&3))
// so MFMA D output lands directly in next step's B-fragment layout -- the
// state never leaves registers except a 1-write/3-read fragment exchange.
// exp(em) fused (no prepass). Rescale: j=0 exponent probe, deferred 1 step.
__global__ __launch_bounds__(256, 1) void crf_fwd_kernel(
    const float* __restrict__ em, const int* __restrict__ lens,
    const float* __restrict__ trans, const float* __restrict__ head,
    const float* __restrict__ last, float* __restrict__ out) {
  const int lane = threadIdx.x & 63;
  const int w = threadIdx.x >> 6;  // wave id
  const int c = lane & 15;         // batch-in-tile
  const int q = lane >> 4;
  const int bg = (int)blockIdx.x * 16 + c;

  __shared__ u32x4 x_lds[2][4][64];  // [pingpong][frag u][lane]
  __shared__ int k_lds[16];
  __shared__ float cap_lds[4][16];

  // E^T fragments (A operand), row-permuted; virtual kt: phys = (w+ktv)&3
  bf16x8 efrag[2][4];
#pragma unroll
  for (int tl = 0; tl < 2; ++tl) {
    const int j = w * 32 + (c >> 2) * 8 + tl * 4 + (c & 3);
#pragma unroll
    for (int ktv = 0; ktv < 4; ++ktv) {
      const int ktp = (w + ktv) & 3;
      u32x4 wd;
#pragma unroll
      for (int p = 0; p < 4; ++p) {
        const int i0 = ktp * 32 + q * 8 + 2 * p;
        wd[p] = pack2_bf16(__expf(trans[(i0 + 0) * N_TAG + j]),
                           __expf(trans[(i0 + 1) * N_TAG + j]));
      }
      efrag[tl][ktv] = __builtin_bit_cast(bf16x8, wd);
    }
  }

  float lastx[8];
#pragma unroll
  for (int jj = 0; jj < 8; ++jj) lastx[jj] = __expf(last[w * 32 + q * 8 + jj]);

  const int len = lens[bg];
  float L = 0.f, Lcap = 0.f;

  // initial state frag u=w: i = 32w + q*8 + jj
  const float* emb = em + (size_t)bg * T_LEN * N_TAG;
  float v0[8];
#pragma unroll
  for (int jj = 0; jj < 8; ++jj) {
    const int i = w * 32 + q * 8 + jj;
    v0[jj] = __expf(head[i] + emb[i]);
  }
  u32x4 bloc;
#pragma unroll
  for (int p = 0; p < 4; ++p) bloc[p] = pack2_bf16(v0[2 * p], v0[2 * p + 1]);
  x_lds[0][w][lane] = bloc;
  if (threadIdx.x < 16) k_lds[threadIdx.x] = 0;

  if (len == 1) {  // edge case (setup guarantees len>=1024, keep correct)
    float s = 0.f;
#pragma unroll
    for (int jj = 0; jj < 8; ++jj) s += v0[jj] * lastx[jj];
    s += __shfl_xor(s, 16);
    s += __shfl_xor(s, 32);
    if (q == 0) cap_lds[w][c] = s;
  }
  __syncthreads();
  if (len == 1 && threadIdx.x < 16)
    out[bg] =
        __logf(cap_lds[0][c] + cap_lds[1][c] + cap_lds[2][c] + cap_lds[3][c]);

  // em prefetch: slot t&3 holds raw em row t (this wave's 8 j's)
  float4 embuf[4][2];
  auto issue_em = [&](int row, int slot) {
    const float4* p =
        (const float4*)(emb + (size_t)row * N_TAG + w * 32 + q * 8);
    embuf[slot][0] = p[0];
    embuf[slot][1] = p[1];
  };
  issue_em(1, 1);
  issue_em(2, 2);
  issue_em(3, 3);

  const f32x4 vzero = {0.f, 0.f, 0.f, 0.f};

  auto step = [&](auto slotc, int t) {
    constexpr int SLOT = decltype(slotc)::value;
    constexpr int RP = (SLOT + 1) & 1;  // read buffer (state of t-1)
    constexpr int WP = SLOT & 1;        // write buffer
    int e = 0;
    if (SLOT == 1) e = k_lds[c];
    // remote fragment reads -- issue immediately after barrier
    const u32x4 bf1 = x_lds[RP][(w + 1) & 3][lane];
    const u32x4 bf2 = x_lds[RP][(w + 2) & 3][lane];
    const u32x4 bf3 = x_lds[RP][(w + 3) & 3][lane];
    {
      int row = t + 3;
      if (row > T_LEN - 1) row = T_LEN - 1;
      issue_em(row, (SLOT + 3) & 3);
    }
    // eem = exp(em_t) -- independent of barrier data, fills the read bubble
    float eemf[8];
    eemf[0] = __expf(embuf[SLOT][0].x);
    eemf[1] = __expf(embuf[SLOT][0].y);
    eemf[2] = __expf(embuf[SLOT][0].z);
    eemf[3] = __expf(embuf[SLOT][0].w);
    eemf[4] = __expf(embuf[SLOT][1].x);
    eemf[5] = __expf(embuf[SLOT][1].y);
    eemf[6] = __expf(embuf[SLOT][1].z);
    eemf[7] = __expf(embuf[SLOT][1].w);
    if (SLOT == 1) {
      // fold 2^-e into eem; L updated BEFORE capture => identical output
      const float sc = __uint_as_float((uint32_t)(127 - e) << 23);
#pragma unroll
      for (int jj = 0; jj < 8; ++jj) eemf[jj] *= sc;
      L += (float)e * 0.6931471805599453f;
    }
    // MFMA: local frag first (no read dependency), two 2-deep chains
    f32x4 a0 = __builtin_amdgcn_mfma_f32_16x16x32_bf16(
        efrag[0][0], __builtin_bit_cast(bf16x8, bloc), vzero, 0, 0, 0);
    f32x4 a1 = __builtin_amdgcn_mfma_f32_16x16x32_bf16(
        efrag[1][0], __builtin_bit_cast(bf16x8, bloc), vzero, 0, 0, 0);
    f32x4 b0 = __builtin_amdgcn_mfma_f32_16x16x32_bf16(
        efrag[0][1], __builtin_bit_cast(bf16x8, bf1), vzero, 0, 0, 0);
    f32x4 b1 = __builtin_amdgcn_mfma_f32_16x16x32_bf16(
        efrag[1][1], __builtin_bit_cast(bf16x8, bf1), vzero, 0, 0, 0);
    a0 = __builtin_amdgcn_mfma_f32_16x16x32_bf16(
        efrag[0][2], __builtin_bit_cast(bf16x8, bf2), a0, 0, 0, 0);
    a1 = __builtin_amdgcn_mfma_f32_16x16x32_bf16(
        efrag[1][2], __builtin_bit_cast(bf16x8, bf2), a1, 0, 0, 0);
    b0 = __builtin_amdgcn_mfma_f32_16x16x32_bf16(
        efrag[0][3], __builtin_bit_cast(bf16x8, bf3), b0, 0, 0, 0);
    b1 = __builtin_amdgcn_mfma_f32_16x16x32_bf16(
        efrag[1][3], __builtin_bit_cast(bf16x8, bf3), b1, 0, 0, 0);
    const f32x4 acc0 = a0 + b0;
    const f32x4 acc1 = a1 + b1;
    // capture: out_b = log(sum_j acc*eem*e^{last}) + L  (this wave's 8 j's)
    if (t == len - 1) {
      float s = acc0[0] * eemf[0] * lastx[0] + acc0[1] * eemf[1] * lastx[1] +
                acc0[2] * eemf[2] * lastx[2] + acc0[3] * eemf[3] * lastx[3] +
                acc1[0] * eemf[4] * lastx[4] + acc1[1] * eemf[5] * lastx[5] +
                acc1[2] * eemf[6] * lastx[6] + acc1[3] * eemf[7] * lastx[7];
      s += __shfl_xor(s, 16);
      s += __shfl_xor(s, 32);
      if (q == 0) cap_lds[w][c] = s;
      Lcap = L;
    }
    if (SLOT == 0) {
      // exponent probe of j=0 (wave 0, q==0 lanes): acc0[0] = alpha[j=0][c]
      if (threadIdx.x < 16)
        k_lds[c] = (int)(__float_as_uint(acc0[0]) >> 23) - 126;
    }
    // pack next state frag (already in B-fragment layout -- lane-local)
    u32x4 wd;
    wd[0] = pack2_bf16(acc0[0] * eemf[0], acc0[1] * eemf[1]);
    wd[1] = pack2_bf16(acc0[2] * eemf[2], acc0[3] * eemf[3]);
    wd[2] = pack2_bf16(acc1[0] * eemf[4], acc1[1] * eemf[5]);
    wd[3] = pack2_bf16(acc1[2] * eemf[6], acc1[3] * eemf[7]);
    bloc = wd;
    x_lds[WP][w][lane] = wd;
    __syncthreads();
    if (t == len - 1 && threadIdx.x < 16)
      out[bg] =
          __logf(cap_lds[0][c] + cap_lds[1][c] + cap_lds[2][c] + cap_lds[3][c]) +
          Lcap;
  };

  int t = 1;
#pragma unroll 1
  for (int it = 0; it < 511; ++it) {  // t = 1 .. 2044
    step(IC<1>{}, t);
    step(IC<2>{}, t + 1);
    step(IC<3>{}, t + 2);
    step(IC<0>{}, t + 3);
    t += 4;
  }
  step(IC<1>{}, t);      // 2045
  step(IC<2>{}, t + 1);  // 2046
  step(IC<3>{}, t + 2);  // 2047
}

extern "C" void kernel_launch(void* const* d_in, const int* in_sizes, int n_in,
                              void* d_out, int out_size, void* d_ws,
                              size_t ws_size, hipStream_t stream) {
  const float* em = (const float*)d_in[0];
  const int* lens = (const int*)d_in[1];
  const float* trans = (const float*)d_in[2];
  const float* head = (const float*)d_in[3];
  const float* last = (const float*)d_in[4];
  float* out = (float*)d_out;
  crf_fwd_kernel<<<4, 256, 0, stream>>>(em, lens, trans, head, last, out);
}